// Round 5
// baseline (165.368 us; speedup 1.0000x reference)
//
#include <hip/hip_runtime.h>
#include <math.h>

// ---------------------------------------------------------------------------
// Reference takes _lstm4(...)[0] -> only t=0 of the whole stack matters.
// With h0=c0=0 each layer is feed-forward: z = x0 @ Wih^T + b,
// c = sigmoid(i)*tanh(g) (f-gate multiplies c0=0 -> dropped),
// h = tanh(sigmoid(o)*tanh(c)).
// R5: weights packed [k][j][{i,g,o}] -> one global_load_dwordx3 per k (was 3
// loads); 1024 threads/block (4 waves/SIMD); split-K partials contiguous per
// output -> ds_read_b128 reductions.
// ---------------------------------------------------------------------------

// ws layout (float offsets). LSTM weights packed (k*H + j)*3 + {0:i,1:g,2:o},
// f-gate dropped. Biases packed j*3+{i,g,o}. FC weights transposed [K][H].
#define O_W1T 0        // 87  x 256 x 3
#define O_W2T 66816    // 256 x 128 x 3
#define O_W3T 165120   // 128 x 64  x 3
#define O_W4T 189696   // 64  x 32  x 3
#define O_F1T 195840   // 32  x 128
#define O_F2T 199936   // 128 x 64
#define O_F3T 208128   // 64  x 32
#define O_B1  210176   // 256 x 3
#define O_B2  210944   // 128 x 3
#define O_B3  211328   // 64  x 3
#define O_B4  211520   // 32  x 3

__global__ __launch_bounds__(256) void prep_kernel(
    const float* __restrict__ w1i, const float* __restrict__ w2i,
    const float* __restrict__ w3i, const float* __restrict__ w4i,
    const float* __restrict__ b1,  const float* __restrict__ b2,
    const float* __restrict__ b3,  const float* __restrict__ b4,
    const float* __restrict__ f1w, const float* __restrict__ f2w,
    const float* __restrict__ f3w, float* __restrict__ ws)
{
    int i = blockIdx.x * 256 + threadIdx.x;
    if (i < 89088) {                                   // w1i [1024 x 87], H=256
        int row = i / 87, k = i - row * 87;
        int g = row >> 8;
        if (g != 1) {
            int gsel = (g == 0) ? 0 : (g == 2) ? 1 : 2;
            ws[O_W1T + (k * 256 + (row & 255)) * 3 + gsel] = w1i[i];
        }
    } else if (i < 220160) {                           // w2i [512 x 256], H=128
        int l = i - 89088;
        int row = l >> 8, k = l & 255;
        int g = row >> 7;
        if (g != 1) {
            int gsel = (g == 0) ? 0 : (g == 2) ? 1 : 2;
            ws[O_W2T + (k * 128 + (row & 127)) * 3 + gsel] = w2i[l];
        }
    } else if (i < 252928) {                           // w3i [256 x 128], H=64
        int l = i - 220160;
        int row = l >> 7, k = l & 127;
        int g = row >> 6;
        if (g != 1) {
            int gsel = (g == 0) ? 0 : (g == 2) ? 1 : 2;
            ws[O_W3T + (k * 64 + (row & 63)) * 3 + gsel] = w3i[l];
        }
    } else if (i < 261120) {                           // w4i [128 x 64], H=32
        int l = i - 252928;
        int row = l >> 6, k = l & 63;
        int g = row >> 5;
        if (g != 1) {
            int gsel = (g == 0) ? 0 : (g == 2) ? 1 : 2;
            ws[O_W4T + (k * 32 + (row & 31)) * 3 + gsel] = w4i[l];
        }
    } else if (i < 262144) {                           // b1 [1024]
        int l = i - 261120;
        int g = l >> 8;
        if (g != 1) {
            int gsel = (g == 0) ? 0 : (g == 2) ? 1 : 2;
            ws[O_B1 + (l & 255) * 3 + gsel] = b1[l];
        }
    } else if (i < 262656) {                           // b2 [512]
        int l = i - 262144;
        int g = l >> 7;
        if (g != 1) {
            int gsel = (g == 0) ? 0 : (g == 2) ? 1 : 2;
            ws[O_B2 + (l & 127) * 3 + gsel] = b2[l];
        }
    } else if (i < 262912) {                           // b3 [256]
        int l = i - 262656;
        int g = l >> 6;
        if (g != 1) {
            int gsel = (g == 0) ? 0 : (g == 2) ? 1 : 2;
            ws[O_B3 + (l & 63) * 3 + gsel] = b3[l];
        }
    } else if (i < 263040) {                           // b4 [128]
        int l = i - 262912;
        int g = l >> 5;
        if (g != 1) {
            int gsel = (g == 0) ? 0 : (g == 2) ? 1 : 2;
            ws[O_B4 + (l & 31) * 3 + gsel] = b4[l];
        }
    } else if (i < 267136) {                           // f1w [128 x 32]
        int l = i - 263040;
        int j = l >> 5, k = l & 31;
        ws[O_F1T + k * 128 + j] = f1w[l];
    } else if (i < 275328) {                           // f2w [64 x 128]
        int l = i - 267136;
        int j = l >> 7, k = l & 127;
        ws[O_F2T + k * 64 + j] = f2w[l];
    } else if (i < 277376) {                           // f3w [32 x 64]
        int l = i - 275328;
        int j = l >> 6, k = l & 63;
        ws[O_F3T + k * 32 + j] = f3w[l];
    }
}

__device__ __forceinline__ float frcp(float x) { return __builtin_amdgcn_rcpf(x); }
__device__ __forceinline__ float sigm(float x) { return frcp(1.0f + __expf(-x)); }
__device__ __forceinline__ float tanh_f(float x) { return 1.0f - 2.0f * frcp(1.0f + __expf(2.0f * x)); }
__device__ __forceinline__ float cell(float zi, float zg, float zo) {
    float c = sigm(zi) * tanh_f(zg);
    return tanh_f(sigm(zo) * tanh_f(c));
}

__global__ __launch_bounds__(1024) void lstm_fused(
    const float* __restrict__ x, const float* __restrict__ ws,
    const float* __restrict__ f1b, const float* __restrict__ f2b,
    const float* __restrict__ f3b, const float* __restrict__ f4w,
    const float* __restrict__ f4b, float* __restrict__ out)
{
    const int t = threadIdx.x;
    const int r = blockIdx.x;                 // one batch row per block

    __shared__ __align__(16) float xs[87];
    __shared__ __align__(16) float h1[256], h2[128], h3[64], h4[32];
    __shared__ __align__(16) float a1[128], a2[64], a3[32];
    __shared__ __align__(16) float ps[3072];  // split-K partials, reused

    if (t < 87) xs[t] = x[r * 87 + t];
    __syncthreads();

    // ---- LSTM1: 87 -> 256, 4-way split-K (22/22/22/21) ----
    {
        const int j = t & 255, q = t >> 8;
        const float3* Wp = (const float3*)(ws + O_W1T);
        float zi = 0.0f, zg = 0.0f, zo = 0.0f;
        const int k0 = q * 22, k1 = (q == 3) ? 87 : (k0 + 22);
        #pragma unroll 8
        for (int k = k0; k < k1; ++k) {
            const float3 w = Wp[k * 256 + j];
            const float xv = xs[k];
            zi = fmaf(xv, w.x, zi);
            zg = fmaf(xv, w.y, zg);
            zo = fmaf(xv, w.z, zo);
        }
        ps[(j * 3 + 0) * 4 + q] = zi;
        ps[(j * 3 + 1) * 4 + q] = zg;
        ps[(j * 3 + 2) * 4 + q] = zo;
    }
    __syncthreads();
    if (t < 256) {
        const float4* p = (const float4*)&ps[t * 12];
        const float4 A = p[0], B = p[1], C = p[2];
        const float* bp = ws + O_B1 + t * 3;
        h1[t] = cell(A.x + A.y + A.z + A.w + bp[0],
                     B.x + B.y + B.z + B.w + bp[1],
                     C.x + C.y + C.z + C.w + bp[2]);
    }
    __syncthreads();

    // ---- LSTM2: 256 -> 128, 8-way split-K ----
    {
        const int j = t & 127, q = t >> 7;
        const float3* Wp = (const float3*)(ws + O_W2T);
        float zi = 0.0f, zg = 0.0f, zo = 0.0f;
        const int k0 = q * 32;
        #pragma unroll 8
        for (int k = k0; k < k0 + 32; ++k) {
            const float3 w = Wp[k * 128 + j];
            const float hv = h1[k];
            zi = fmaf(hv, w.x, zi);
            zg = fmaf(hv, w.y, zg);
            zo = fmaf(hv, w.z, zo);
        }
        ps[(j * 3 + 0) * 8 + q] = zi;
        ps[(j * 3 + 1) * 8 + q] = zg;
        ps[(j * 3 + 2) * 8 + q] = zo;
    }
    __syncthreads();
    if (t < 128) {
        const float4* p = (const float4*)&ps[t * 24];
        const float4 A0 = p[0], A1 = p[1], B0 = p[2], B1 = p[3], C0 = p[4], C1 = p[5];
        const float* bp = ws + O_B2 + t * 3;
        h2[t] = cell(A0.x + A0.y + A0.z + A0.w + A1.x + A1.y + A1.z + A1.w + bp[0],
                     B0.x + B0.y + B0.z + B0.w + B1.x + B1.y + B1.z + B1.w + bp[1],
                     C0.x + C0.y + C0.z + C0.w + C1.x + C1.y + C1.z + C1.w + bp[2]);
    }
    __syncthreads();

    // ---- LSTM3: 128 -> 64, 16-way split-K ----
    {
        const int j = t & 63, q = t >> 6;
        const float3* Wp = (const float3*)(ws + O_W3T);
        float zi = 0.0f, zg = 0.0f, zo = 0.0f;
        const int k0 = q * 8;
        #pragma unroll
        for (int k = k0; k < k0 + 8; ++k) {
            const float3 w = Wp[k * 64 + j];
            const float hv = h2[k];
            zi = fmaf(hv, w.x, zi);
            zg = fmaf(hv, w.y, zg);
            zo = fmaf(hv, w.z, zo);
        }
        ps[(j * 3 + 0) * 16 + q] = zi;
        ps[(j * 3 + 1) * 16 + q] = zg;
        ps[(j * 3 + 2) * 16 + q] = zo;
    }
    __syncthreads();
    if (t < 64) {
        const float4* p = (const float4*)&ps[t * 48];
        float z[3];
        #pragma unroll
        for (int g = 0; g < 3; ++g) {
            const float4 v0 = p[g * 4], v1 = p[g * 4 + 1], v2 = p[g * 4 + 2], v3 = p[g * 4 + 3];
            z[g] = (v0.x + v0.y + v0.z + v0.w) + (v1.x + v1.y + v1.z + v1.w)
                 + (v2.x + v2.y + v2.z + v2.w) + (v3.x + v3.y + v3.z + v3.w);
        }
        const float* bp = ws + O_B3 + t * 3;
        h3[t] = cell(z[0] + bp[0], z[1] + bp[1], z[2] + bp[2]);
    }
    __syncthreads();

    // ---- LSTM4: 64 -> 32, 8-way split-K (threads 0..255) ----
    if (t < 256) {
        const int j = t & 31, q = t >> 5;
        const float3* Wp = (const float3*)(ws + O_W4T);
        float zi = 0.0f, zg = 0.0f, zo = 0.0f;
        const int k0 = q * 8;
        #pragma unroll
        for (int k = k0; k < k0 + 8; ++k) {
            const float3 w = Wp[k * 32 + j];
            const float hv = h3[k];
            zi = fmaf(hv, w.x, zi);
            zg = fmaf(hv, w.y, zg);
            zo = fmaf(hv, w.z, zo);
        }
        ps[(j * 3 + 0) * 8 + q] = zi;
        ps[(j * 3 + 1) * 8 + q] = zg;
        ps[(j * 3 + 2) * 8 + q] = zo;
    }
    __syncthreads();
    if (t < 32) {
        const float4* p = (const float4*)&ps[t * 24];
        const float4 A0 = p[0], A1 = p[1], B0 = p[2], B1 = p[3], C0 = p[4], C1 = p[5];
        const float* bp = ws + O_B4 + t * 3;
        h4[t] = cell(A0.x + A0.y + A0.z + A0.w + A1.x + A1.y + A1.z + A1.w + bp[0],
                     B0.x + B0.y + B0.z + B0.w + B1.x + B1.y + B1.z + B1.w + bp[1],
                     C0.x + C0.y + C0.z + C0.w + C1.x + C1.y + C1.z + C1.w + bp[2]);
    }
    __syncthreads();

    // ---- FC1: 32 -> 128, relu, 8-way split-K ----
    {
        const int j = t & 127, q = t >> 7;
        const float* F = ws + O_F1T;
        float a = 0.0f;
        const int k0 = q * 4;
        #pragma unroll
        for (int k = k0; k < k0 + 4; ++k)
            a = fmaf(h4[k], F[k * 128 + j], a);
        ps[j * 8 + q] = a;
    }
    __syncthreads();
    if (t < 128) {
        const float4* p = (const float4*)&ps[t * 8];
        const float4 A = p[0], B = p[1];
        a1[t] = fmaxf(A.x + A.y + A.z + A.w + B.x + B.y + B.z + B.w + f1b[t], 0.0f);
    }
    __syncthreads();

    // ---- FC2: 128 -> 64, relu, 16-way split-K ----
    {
        const int j = t & 63, q = t >> 6;
        const float* F = ws + O_F2T;
        float a = 0.0f;
        const int k0 = q * 8;
        #pragma unroll
        for (int k = k0; k < k0 + 8; ++k)
            a = fmaf(a1[k], F[k * 64 + j], a);
        ps[j * 16 + q] = a;
    }
    __syncthreads();
    if (t < 64) {
        const float4* p = (const float4*)&ps[t * 16];
        const float4 A = p[0], B = p[1], C = p[2], D = p[3];
        a2[t] = fmaxf((A.x + A.y + A.z + A.w) + (B.x + B.y + B.z + B.w)
                    + (C.x + C.y + C.z + C.w) + (D.x + D.y + D.z + D.w) + f2b[t], 0.0f);
    }
    __syncthreads();

    // ---- FC3: 64 -> 32, relu, 8-way split-K (threads 0..255) ----
    if (t < 256) {
        const int j = t & 31, q = t >> 5;
        const float* F = ws + O_F3T;
        float a = 0.0f;
        const int k0 = q * 8;
        #pragma unroll
        for (int k = k0; k < k0 + 8; ++k)
            a = fmaf(a2[k], F[k * 32 + j], a);
        ps[j * 8 + q] = a;
    }
    __syncthreads();
    if (t < 32) {
        const float4* p = (const float4*)&ps[t * 8];
        const float4 A = p[0], B = p[1];
        a3[t] = fmaxf(A.x + A.y + A.z + A.w + B.x + B.y + B.z + B.w + f3b[t], 0.0f);
    }
    __syncthreads();

    // ---- FC4: 32 -> 3, 8-way split-K (threads 0..31) ----
    if (t < 32) {
        const int o = t & 3, q = t >> 2;
        float a = 0.0f;
        if (o < 3) {
            const int k0 = q * 4;
            #pragma unroll
            for (int k = k0; k < k0 + 4; ++k)
                a = fmaf(a3[k], f4w[o * 32 + k], a);
        }
        ps[o * 8 + q] = a;
    }
    __syncthreads();
    if (t < 3) {
        const float4* p = (const float4*)&ps[t * 8];
        const float4 A = p[0], B = p[1];
        out[r * 3 + t] = A.x + A.y + A.z + A.w + B.x + B.y + B.z + B.w + f4b[t];
    }
}

extern "C" void kernel_launch(void* const* d_in, const int* in_sizes, int n_in,
                              void* d_out, int out_size, void* d_ws, size_t ws_size,
                              hipStream_t stream) {
    const float* x   = (const float*)d_in[0];
    const float* w1i = (const float*)d_in[1];
    const float* b1  = (const float*)d_in[3];
    const float* w2i = (const float*)d_in[4];
    const float* b2  = (const float*)d_in[6];
    const float* w3i = (const float*)d_in[7];
    const float* b3  = (const float*)d_in[9];
    const float* w4i = (const float*)d_in[10];
    const float* b4  = (const float*)d_in[12];
    const float* f1w = (const float*)d_in[13];
    const float* f1b = (const float*)d_in[14];
    const float* f2w = (const float*)d_in[15];
    const float* f2b = (const float*)d_in[16];
    const float* f3w = (const float*)d_in[17];
    const float* f3b = (const float*)d_in[18];
    const float* f4w = (const float*)d_in[19];
    const float* f4b = (const float*)d_in[20];
    float* ws  = (float*)d_ws;
    float* out = (float*)d_out;

    prep_kernel<<<1084, 256, 0, stream>>>(w1i, w2i, w3i, w4i, b1, b2, b3, b4,
                                          f1w, f2w, f3w, ws);
    // one batch row per block, 1024 threads (4 waves/SIMD for latency hiding)
    lstm_fused<<<256, 1024, 0, stream>>>(x, ws, f1b, f2b, f3b, f4w, f4b, out);
}

// Round 6
// 164.523 us; speedup vs baseline: 1.0051x; 1.0051x over previous
//
#include <hip/hip_runtime.h>
#include <math.h>

// ---------------------------------------------------------------------------
// Reference takes _lstm4(...)[0] -> only t=0 of the whole stack matters.
// With h0=c0=0 each layer is feed-forward: z = x0 @ Wih^T + b,
// c = sigmoid(i)*tanh(g) (f-gate multiplies c0=0 -> dropped),
// h = tanh(sigmoid(o)*tanh(c)).
// R6 = revert to R4 (best measured, 163.0 us): 512 threads/block
// (2 waves/SIMD), split-K per layer, critical path ~188 loop iterations.
// R5's 1024-thread + float3 variant measured 165.4 -> reverted.
// ---------------------------------------------------------------------------

// ws layout (float offsets). Weights transposed to [K][3H], f-gate dropped,
// packed gate order: i | g | o.
#define O_W1T 0        // 87  x 768
#define O_W2T 66816    // 256 x 384
#define O_W3T 165120   // 128 x 192
#define O_W4T 189696   // 64  x 96
#define O_F1T 195840   // 32  x 128
#define O_F2T 199936   // 128 x 64
#define O_F3T 208128   // 64  x 32
#define O_B1  210176   // 768
#define O_B2  210944   // 384
#define O_B3  211328   // 192
#define O_B4  211520   // 96

__global__ __launch_bounds__(256) void prep_kernel(
    const float* __restrict__ w1i, const float* __restrict__ w2i,
    const float* __restrict__ w3i, const float* __restrict__ w4i,
    const float* __restrict__ b1,  const float* __restrict__ b2,
    const float* __restrict__ b3,  const float* __restrict__ b4,
    const float* __restrict__ f1w, const float* __restrict__ f2w,
    const float* __restrict__ f3w, float* __restrict__ ws)
{
    int i = blockIdx.x * 256 + threadIdx.x;
    if (i < 89088) {                                   // w1i [1024 x 87], H=256
        int row = i / 87, k = i - row * 87;
        int g = row >> 8;
        if (g != 1) {
            int base = (g == 0) ? 0 : (g == 2) ? 256 : 512;
            ws[O_W1T + k * 768 + base + (row & 255)] = w1i[i];
        }
    } else if (i < 220160) {                           // w2i [512 x 256], H=128
        int l = i - 89088;
        int row = l >> 8, k = l & 255;
        int g = row >> 7;
        if (g != 1) {
            int base = (g == 0) ? 0 : (g == 2) ? 128 : 256;
            ws[O_W2T + k * 384 + base + (row & 127)] = w2i[l];
        }
    } else if (i < 252928) {                           // w3i [256 x 128], H=64
        int l = i - 220160;
        int row = l >> 7, k = l & 127;
        int g = row >> 6;
        if (g != 1) {
            int base = (g == 0) ? 0 : (g == 2) ? 64 : 128;
            ws[O_W3T + k * 192 + base + (row & 63)] = w3i[l];
        }
    } else if (i < 261120) {                           // w4i [128 x 64], H=32
        int l = i - 252928;
        int row = l >> 6, k = l & 63;
        int g = row >> 5;
        if (g != 1) {
            int base = (g == 0) ? 0 : (g == 2) ? 32 : 64;
            ws[O_W4T + k * 96 + base + (row & 31)] = w4i[l];
        }
    } else if (i < 262144) {                           // b1 [1024]
        int l = i - 261120;
        int g = l >> 8;
        if (g != 1) {
            int base = (g == 0) ? 0 : (g == 2) ? 256 : 512;
            ws[O_B1 + base + (l & 255)] = b1[l];
        }
    } else if (i < 262656) {                           // b2 [512]
        int l = i - 262144;
        int g = l >> 7;
        if (g != 1) {
            int base = (g == 0) ? 0 : (g == 2) ? 128 : 256;
            ws[O_B2 + base + (l & 127)] = b2[l];
        }
    } else if (i < 262912) {                           // b3 [256]
        int l = i - 262656;
        int g = l >> 6;
        if (g != 1) {
            int base = (g == 0) ? 0 : (g == 2) ? 64 : 128;
            ws[O_B3 + base + (l & 63)] = b3[l];
        }
    } else if (i < 263040) {                           // b4 [128]
        int l = i - 262912;
        int g = l >> 5;
        if (g != 1) {
            int base = (g == 0) ? 0 : (g == 2) ? 32 : 64;
            ws[O_B4 + base + (l & 31)] = b4[l];
        }
    } else if (i < 267136) {                           // f1w [128 x 32]
        int l = i - 263040;
        int j = l >> 5, k = l & 31;
        ws[O_F1T + k * 128 + j] = f1w[l];
    } else if (i < 275328) {                           // f2w [64 x 128]
        int l = i - 267136;
        int j = l >> 7, k = l & 127;
        ws[O_F2T + k * 64 + j] = f2w[l];
    } else if (i < 277376) {                           // f3w [32 x 64]
        int l = i - 275328;
        int j = l >> 6, k = l & 63;
        ws[O_F3T + k * 32 + j] = f3w[l];
    }
}

__device__ __forceinline__ float frcp(float x) { return __builtin_amdgcn_rcpf(x); }
__device__ __forceinline__ float sigm(float x) { return frcp(1.0f + __expf(-x)); }
__device__ __forceinline__ float tanh_f(float x) { return 1.0f - 2.0f * frcp(1.0f + __expf(2.0f * x)); }
__device__ __forceinline__ float cell(float zi, float zg, float zo) {
    float c = sigm(zi) * tanh_f(zg);
    return tanh_f(sigm(zo) * tanh_f(c));
}

__global__ __launch_bounds__(512) void lstm_fused(
    const float* __restrict__ x, const float* __restrict__ ws,
    const float* __restrict__ f1b, const float* __restrict__ f2b,
    const float* __restrict__ f3b, const float* __restrict__ f4w,
    const float* __restrict__ f4b, float* __restrict__ out)
{
    const int t = threadIdx.x;
    const int r = blockIdx.x;                 // one batch row per block

    __shared__ float xs[87];
    __shared__ float h1[256], h2[128], h3[64], h4[32];
    __shared__ float a1[128], a2[64], a3[32];
    __shared__ float ps[1536];                // split-K partials, reused

    const float* W1T = ws + O_W1T;
    const float* W2T = ws + O_W2T;
    const float* W3T = ws + O_W3T;
    const float* W4T = ws + O_W4T;
    const float* F1T = ws + O_F1T;
    const float* F2T = ws + O_F2T;
    const float* F3T = ws + O_F3T;
    const float* B1p = ws + O_B1;
    const float* B2p = ws + O_B2;
    const float* B3p = ws + O_B3;
    const float* B4p = ws + O_B4;

    if (t < 87) xs[t] = x[r * 87 + t];
    __syncthreads();

    // ---- LSTM1: 87 -> 256, 2-way split-K (44 / 43) ----
    {
        const int j = t & 255, q = t >> 8;
        float zi = q ? 0.0f : B1p[j];
        float zg = q ? 0.0f : B1p[256 + j];
        float zo = q ? 0.0f : B1p[512 + j];
        const float* w = W1T + j;
        const int k0 = q ? 44 : 0, k1 = q ? 87 : 44;
        #pragma unroll 8
        for (int k = k0; k < k1; ++k) {
            const float xv = xs[k];
            zi = fmaf(xv, w[k * 768],       zi);
            zg = fmaf(xv, w[k * 768 + 256], zg);
            zo = fmaf(xv, w[k * 768 + 512], zo);
        }
        ps[q * 768 + j]       = zi;
        ps[q * 768 + 256 + j] = zg;
        ps[q * 768 + 512 + j] = zo;
    }
    __syncthreads();
    if (t < 256)
        h1[t] = cell(ps[t] + ps[768 + t],
                     ps[256 + t] + ps[1024 + t],
                     ps[512 + t] + ps[1280 + t]);
    __syncthreads();

    // ---- LSTM2: 256 -> 128, 4-way split-K ----
    {
        const int j = t & 127, q = t >> 7;
        float zi = q ? 0.0f : B2p[j];
        float zg = q ? 0.0f : B2p[128 + j];
        float zo = q ? 0.0f : B2p[256 + j];
        const float* w = W2T + j;
        const int k0 = q * 64;
        #pragma unroll 8
        for (int k = k0; k < k0 + 64; ++k) {
            const float hv = h1[k];
            zi = fmaf(hv, w[k * 384],       zi);
            zg = fmaf(hv, w[k * 384 + 128], zg);
            zo = fmaf(hv, w[k * 384 + 256], zo);
        }
        ps[q * 384 + j]       = zi;
        ps[q * 384 + 128 + j] = zg;
        ps[q * 384 + 256 + j] = zo;
    }
    __syncthreads();
    if (t < 128) {
        float zi = 0.0f, zg = 0.0f, zo = 0.0f;
        #pragma unroll
        for (int q = 0; q < 4; ++q) {
            zi += ps[q * 384 + t];
            zg += ps[q * 384 + 128 + t];
            zo += ps[q * 384 + 256 + t];
        }
        h2[t] = cell(zi, zg, zo);
    }
    __syncthreads();

    // ---- LSTM3: 128 -> 64, 8-way split-K ----
    {
        const int j = t & 63, q = t >> 6;
        float zi = q ? 0.0f : B3p[j];
        float zg = q ? 0.0f : B3p[64 + j];
        float zo = q ? 0.0f : B3p[128 + j];
        const float* w = W3T + j;
        const int k0 = q * 16;
        #pragma unroll
        for (int k = k0; k < k0 + 16; ++k) {
            const float hv = h2[k];
            zi = fmaf(hv, w[k * 192],       zi);
            zg = fmaf(hv, w[k * 192 + 64],  zg);
            zo = fmaf(hv, w[k * 192 + 128], zo);
        }
        ps[q * 192 + j]       = zi;
        ps[q * 192 + 64 + j]  = zg;
        ps[q * 192 + 128 + j] = zo;
    }
    __syncthreads();
    if (t < 64) {
        float zi = 0.0f, zg = 0.0f, zo = 0.0f;
        #pragma unroll
        for (int q = 0; q < 8; ++q) {
            zi += ps[q * 192 + t];
            zg += ps[q * 192 + 64 + t];
            zo += ps[q * 192 + 128 + t];
        }
        h3[t] = cell(zi, zg, zo);
    }
    __syncthreads();

    // ---- LSTM4: 64 -> 32, 16-way split-K ----
    {
        const int j = t & 31, q = t >> 5;
        float zi = (q == 0) ? B4p[j] : 0.0f;
        float zg = (q == 0) ? B4p[32 + j] : 0.0f;
        float zo = (q == 0) ? B4p[64 + j] : 0.0f;
        const float* w = W4T + j;
        const int k0 = q * 4;
        #pragma unroll
        for (int k = k0; k < k0 + 4; ++k) {
            const float hv = h3[k];
            zi = fmaf(hv, w[k * 96],      zi);
            zg = fmaf(hv, w[k * 96 + 32], zg);
            zo = fmaf(hv, w[k * 96 + 64], zo);
        }
        ps[q * 96 + j]      = zi;
        ps[q * 96 + 32 + j] = zg;
        ps[q * 96 + 64 + j] = zo;
    }
    __syncthreads();
    if (t < 32) {
        float zi = 0.0f, zg = 0.0f, zo = 0.0f;
        #pragma unroll
        for (int q = 0; q < 16; ++q) {
            zi += ps[q * 96 + t];
            zg += ps[q * 96 + 32 + t];
            zo += ps[q * 96 + 64 + t];
        }
        h4[t] = cell(zi, zg, zo);
    }
    __syncthreads();

    // ---- FC1: 32 -> 128, relu, 4-way split-K ----
    {
        const int j = t & 127, q = t >> 7;
        float a = q ? 0.0f : f1b[j];
        const int k0 = q * 8;
        #pragma unroll
        for (int k = k0; k < k0 + 8; ++k)
            a = fmaf(h4[k], F1T[k * 128 + j], a);
        ps[q * 128 + j] = a;
    }
    __syncthreads();
    if (t < 128)
        a1[t] = fmaxf(ps[t] + ps[128 + t] + ps[256 + t] + ps[384 + t], 0.0f);
    __syncthreads();

    // ---- FC2: 128 -> 64, relu, 8-way split-K ----
    {
        const int j = t & 63, q = t >> 6;
        float a = q ? 0.0f : f2b[j];
        const int k0 = q * 16;
        #pragma unroll
        for (int k = k0; k < k0 + 16; ++k)
            a = fmaf(a1[k], F2T[k * 64 + j], a);
        ps[q * 64 + j] = a;
    }
    __syncthreads();
    if (t < 64) {
        float a = 0.0f;
        #pragma unroll
        for (int q = 0; q < 8; ++q) a += ps[q * 64 + t];
        a2[t] = fmaxf(a, 0.0f);
    }
    __syncthreads();

    // ---- FC3: 64 -> 32, relu, 16-way split-K ----
    {
        const int j = t & 31, q = t >> 5;
        float a = (q == 0) ? f3b[j] : 0.0f;
        const int k0 = q * 4;
        #pragma unroll
        for (int k = k0; k < k0 + 4; ++k)
            a = fmaf(a2[k], F3T[k * 32 + j], a);
        ps[q * 32 + j] = a;
    }
    __syncthreads();
    if (t < 32) {
        float a = 0.0f;
        #pragma unroll
        for (int q = 0; q < 16; ++q) a += ps[q * 32 + t];
        a3[t] = fmaxf(a, 0.0f);
    }
    __syncthreads();

    // ---- FC4: 32 -> 3 ----
    if (t < 3) {
        float a = f4b[t];
        const float* w = f4w + t * 32;
        #pragma unroll
        for (int k = 0; k < 32; ++k)
            a = fmaf(a3[k], w[k], a);
        out[r * 3 + t] = a;
    }
}

extern "C" void kernel_launch(void* const* d_in, const int* in_sizes, int n_in,
                              void* d_out, int out_size, void* d_ws, size_t ws_size,
                              hipStream_t stream) {
    const float* x   = (const float*)d_in[0];
    const float* w1i = (const float*)d_in[1];
    const float* b1  = (const float*)d_in[3];
    const float* w2i = (const float*)d_in[4];
    const float* b2  = (const float*)d_in[6];
    const float* w3i = (const float*)d_in[7];
    const float* b3  = (const float*)d_in[9];
    const float* w4i = (const float*)d_in[10];
    const float* b4  = (const float*)d_in[12];
    const float* f1w = (const float*)d_in[13];
    const float* f1b = (const float*)d_in[14];
    const float* f2w = (const float*)d_in[15];
    const float* f2b = (const float*)d_in[16];
    const float* f3w = (const float*)d_in[17];
    const float* f3b = (const float*)d_in[18];
    const float* f4w = (const float*)d_in[19];
    const float* f4b = (const float*)d_in[20];
    float* ws  = (float*)d_ws;
    float* out = (float*)d_out;

    prep_kernel<<<1084, 256, 0, stream>>>(w1i, w2i, w3i, w4i, b1, b2, b3, b4,
                                          f1w, f2w, f3w, ws);
    // one batch row per block, 512 threads (2 waves/SIMD for latency hiding)
    lstm_fused<<<256, 512, 0, stream>>>(x, ws, f1b, f2b, f3b, f4w, f4b, out);
}